// Round 1
// 213.007 us; speedup vs baseline: 1.0083x; 1.0083x over previous
//
#include <hip/hip_runtime.h>
#include <cmath>

// FSEncLoss on gfx950 — dense-stream fused kernel.
// loss = mean over (block, c) of [ softplus(x) - t*x ],
//   t = 1 iff class c appears in the 8x8 target block.
// B=16, H=1024, W=2048, G=8, NUM_CLASSES=19.
//
// R7 theory: previous kernel's NT loads were per-instruction SPARSE
// (targets: 16B @ 32B stride, 50% dense; preds: 16B @ 76B stride, 21% dense)
// and `nt` (no-allocate) defeats the L1/L2 granule merging those patterns
// depend on -> ~450MB effective HBM demand instead of 174MB -> ~2.7 TB/s
// apparent read cap. This version makes EVERY load instruction lane-dense
// (64 lanes x 16B = 1KB contiguous), so each byte is fetched exactly once
// and NT is harmless:
//   targets: thread t loads chunk t and chunk 256+t of each of 8 rows
//            (each instruction = dense 1KB; whole WG band = 64KB dense).
//            Thread t's data belongs to blocks t>>1 and 128+(t>>1):
//            build 2 partial masks, pair-combine via shfl_xor(1), publish
//            per-block masks through LDS (1KB, one barrier).
//   preds:   dense float4 stream, 1216 f4 per band exactly; per element
//            block = g/19 (magic-mul), class = g%19, mask from LDS.
//            5th load covers f4 1024..1215 -> t<192 = waves 0..2 only,
//            wave-uniform, no divergence.

typedef int   i4v __attribute__((ext_vector_type(4), aligned(16)));
typedef float f4v __attribute__((ext_vector_type(4), aligned(16)));

__global__ __launch_bounds__(256) void fsenc_loss_kernel(
    const float* __restrict__ preds,
    const int*   __restrict__ targets,
    float*       __restrict__ out,
    float inv_count)
{
    const int t    = threadIdx.x;
    const int band = blockIdx.x;               // 2048 bands (B*H/8)

    // ---- targets: dense 16B/lane loads; 512 i4 chunks per row ----
    const i4v* tb = (const i4v*)targets + (long)band * 4096;  // 4096 i4/band
    i4v ta[8], tc[8];
    #pragma unroll
    for (int r = 0; r < 8; ++r) {
        ta[r] = __builtin_nontemporal_load(tb + r * 512 + t);        // chunks 0..255
        tc[r] = __builtin_nontemporal_load(tb + r * 512 + 256 + t);  // chunks 256..511
    }

    // ---- preds: dense float4 stream, 1216 f4/band (= 256*19 floats) ----
    const f4v* pb = (const f4v*)preds + (long)band * 1216;
    f4v q[5];
    #pragma unroll
    for (int k = 0; k < 4; ++k)
        q[k] = __builtin_nontemporal_load(pb + t + 256 * k);
    const bool has5 = (t < 192);               // wave-uniform (waves 0..2)
    if (has5) q[4] = __builtin_nontemporal_load(pb + t + 1024);

    // ---- partial presence masks: chunk t -> block t>>1, chunk 256+t -> 128+(t>>1)
    unsigned mA = 0u, mB = 0u;
    #pragma unroll
    for (int r = 0; r < 8; ++r) {
        i4v u = ta[r];
        mA |= (1u << u[0]) | (1u << u[1]) | (1u << u[2]) | (1u << u[3]);
        i4v v = tc[r];
        mB |= (1u << v[0]) | (1u << v[1]) | (1u << v[2]) | (1u << v[3]);
    }
    // pair (2b, 2b+1) both hold block b's full mask after xor-1 combine
    mA |= __shfl_xor(mA, 1);
    mB |= __shfl_xor(mB, 1);

    __shared__ unsigned s_mask[256];
    if ((t & 1) == 0) {
        s_mask[t >> 1]         = mA;           // blocks 0..127
        s_mask[128 + (t >> 1)] = mB;           // blocks 128..255
    }
    __syncthreads();

    // ---- softplus(x) - t*x over the dense pred stream ----
    float acc = 0.f;
    #define SP_TERM(xval, gidx)                                                \
        {                                                                      \
            float x_ = (xval);                                                 \
            unsigned g_ = (unsigned)(gidx);                                    \
            unsigned blk_ = g_ / 19u;                                          \
            unsigned cls_ = g_ - blk_ * 19u;                                   \
            float sp_ = fmaxf(x_, 0.f) + __logf(1.f + __expf(-fabsf(x_)));     \
            acc += sp_ - (float)((s_mask[blk_] >> cls_) & 1u) * x_;            \
        }
    #pragma unroll
    for (int k = 0; k < 4; ++k) {
        int g0 = 4 * (t + 256 * k);
        SP_TERM(q[k][0], g0)     SP_TERM(q[k][1], g0 + 1)
        SP_TERM(q[k][2], g0 + 2) SP_TERM(q[k][3], g0 + 3)
    }
    if (has5) {
        int g0 = 4 * (t + 1024);
        SP_TERM(q[4][0], g0)     SP_TERM(q[4][1], g0 + 1)
        SP_TERM(q[4][2], g0 + 2) SP_TERM(q[4][3], g0 + 3)
    }
    #undef SP_TERM

    // ---- reduce: wave (64) -> workgroup -> one atomic ----
    #pragma unroll
    for (int off = 32; off; off >>= 1)
        acc += __shfl_down(acc, off);

    __shared__ float s_part[4];
    if ((t & 63) == 0) s_part[t >> 6] = acc;
    __syncthreads();
    if (t == 0) {
        float tot = s_part[0] + s_part[1] + s_part[2] + s_part[3];
        atomicAdd(out, tot * inv_count);
    }
}

extern "C" void kernel_launch(void* const* d_in, const int* in_sizes, int n_in,
                              void* d_out, int out_size, void* d_ws, size_t ws_size,
                              hipStream_t stream) {
    const float* preds   = (const float*)d_in[0];
    const int*   targets = (const int*)d_in[1];
    float*       out     = (float*)d_out;

    const int B = 16, H = 1024;
    const float inv_count = 1.0f / (float)in_sizes[0];   // n_blocks * 19

    (void)hipMemsetAsync(out, 0, sizeof(float), stream);

    const int grid = B * (H / 8);                 // 2048 bands
    fsenc_loss_kernel<<<grid, 256, 0, stream>>>(preds, targets, out, inv_count);
}